// Round 1
// baseline (156.721 us; speedup 1.0000x reference)
//
#include <hip/hip_runtime.h>
#include <math.h>

#define BB 64
#define TT 2048
#define RNN 1024
#define EMB 512
#define ATTN 128
#define NF 32
#define KS 31
#define PADW 15

#define TILE_T 256
#define NSEG 16
#define SEG_T (TT / NSEG)  // 128

// ---------------------------------------------------------------------------
// Kernel 1: pq[b][a] = sum_r h[b][r] * Wq[a][r]
// grid = B, block = 256 (4 waves, each wave does 32 outputs)
// ---------------------------------------------------------------------------
__global__ __launch_bounds__(256) void pq_kernel(const float* __restrict__ h,
                                                 const float* __restrict__ Wq,
                                                 float* __restrict__ pq) {
    int b = blockIdx.x;
    __shared__ float s_h[RNN];
    for (int i = threadIdx.x; i < RNN; i += 256) s_h[i] = h[b * RNN + i];
    __syncthreads();

    int wave = threadIdx.x >> 6;
    int lane = threadIdx.x & 63;
    for (int j = 0; j < 32; ++j) {
        int a = wave * 32 + j;
        const float4* wq4 = (const float4*)(Wq + (size_t)a * RNN);
        float acc = 0.f;
#pragma unroll
        for (int i = 0; i < 4; ++i) {
            float4 w4 = wq4[lane + 64 * i];
            float4 h4 = *(const float4*)(s_h + 4 * (lane + 64 * i));
            acc += w4.x * h4.x + w4.y * h4.y + w4.z * h4.z + w4.w * h4.w;
        }
#pragma unroll
        for (int off = 32; off > 0; off >>= 1) acc += __shfl_xor(acc, off, 64);
        if (lane == 0) pq[b * ATTN + a] = acc;
    }
}

// ---------------------------------------------------------------------------
// Kernel 2: energies[b][t] = sum_a Wv[a]*tanh(pq[b][a] + ploc[b][t][a] + pm[b][t][a])
//   where ploc = (conv1d(awc, Wconv)) @ WlocT
// grid = B * (T/TILE_T) = 512, block = 256
// ---------------------------------------------------------------------------
__global__ __launch_bounds__(256) void energy_kernel(
    const float* __restrict__ pm,     // [B][T][ATTN]
    const float* __restrict__ awc,    // [B][2][T]
    const float* __restrict__ pq,     // [B][ATTN]
    const float* __restrict__ Wconv,  // [NF][2][KS]
    const float* __restrict__ Wloc,   // [ATTN][NF]
    const float* __restrict__ Wv,     // [ATTN]
    float* __restrict__ energies)     // [B][T]
{
    int b = blockIdx.x >> 3;           // 8 tiles per batch row
    int t0 = (blockIdx.x & 7) * TILE_T;
    int tid = threadIdx.x;

    __shared__ float s_awc[2][TILE_T + 2 * PADW];  // 2 x 286
    __shared__ float s_conv[TILE_T][36];           // pad 36 -> 144B row, 16B aligned

    // stage awc window (zero-padded at sequence edges)
    for (int i = tid; i < 2 * (TILE_T + 2 * PADW); i += 256) {
        int c = i / (TILE_T + 2 * PADW);
        int j = i % (TILE_T + 2 * PADW);
        int tg = t0 - PADW + j;
        s_awc[c][j] = (tg >= 0 && tg < TT) ? awc[((size_t)b * 2 + c) * TT + tg] : 0.f;
    }
    __syncthreads();

    // ---- phase A: conv, thread owns t = tid ----
    float aw[2][KS];
#pragma unroll
    for (int c = 0; c < 2; ++c)
#pragma unroll
        for (int k = 0; k < KS; ++k) aw[c][k] = s_awc[c][tid + k];

#pragma unroll
    for (int f = 0; f < NF; ++f) {
        float acc = 0.f;
#pragma unroll
        for (int c = 0; c < 2; ++c)
#pragma unroll
            for (int k = 0; k < KS; ++k)
                acc += aw[c][k] * Wconv[(f * 2 + c) * KS + k];  // uniform -> s_load
        s_conv[tid][f] = acc;
    }
    __syncthreads();

    // ---- phase B: wave owns t, lane owns attention dims (lane, lane+64) ----
    int wave = tid >> 6;
    int lane = tid & 63;

    float wl0[NF], wl1[NF];
#pragma unroll
    for (int f = 0; f < NF; ++f) {
        wl0[f] = Wloc[lane * NF + f];          // L2-resident (16 KB total)
        wl1[f] = Wloc[(lane + 64) * NF + f];
    }
    float pq0 = pq[b * ATTN + lane], pq1 = pq[b * ATTN + lane + 64];
    float wv0 = Wv[lane], wv1 = Wv[lane + 64];

    for (int i = 0; i < 64; ++i) {
        int tl = wave * 64 + i;
        int tg = t0 + tl;
        float v0 = pq0, v1 = pq1;
        const float4* cv4 = (const float4*)&s_conv[tl][0];  // uniform -> broadcast
#pragma unroll
        for (int f4 = 0; f4 < 8; ++f4) {
            float4 cv = cv4[f4];
            v0 += cv.x * wl0[f4 * 4 + 0] + cv.y * wl0[f4 * 4 + 1] +
                  cv.z * wl0[f4 * 4 + 2] + cv.w * wl0[f4 * 4 + 3];
            v1 += cv.x * wl1[f4 * 4 + 0] + cv.y * wl1[f4 * 4 + 1] +
                  cv.z * wl1[f4 * 4 + 2] + cv.w * wl1[f4 * 4 + 3];
        }
        const float* pmrow = pm + ((size_t)(b * TT + tg)) * ATTN;
        v0 += pmrow[lane];        // coalesced 256B
        v1 += pmrow[lane + 64];   // coalesced 256B
        float e = wv0 * tanhf(v0) + wv1 * tanhf(v1);
#pragma unroll
        for (int off = 32; off > 0; off >>= 1) e += __shfl_xor(e, off, 64);
        if (lane == 0) energies[b * TT + tg] = e;
    }
}

// ---------------------------------------------------------------------------
// Kernel 3: softmax over T per batch row; writes weights to d_out region
// grid = B, block = 256 (each thread handles 8 t)
// ---------------------------------------------------------------------------
__global__ __launch_bounds__(256) void softmax_kernel(
    const float* __restrict__ energies, const unsigned char* __restrict__ mask,
    float* __restrict__ w) {
    int b = blockIdx.x, tid = threadIdx.x;
    __shared__ float s_red[8];

    float v[8];
    float m = -1e30f;
#pragma unroll
    for (int i = 0; i < 8; ++i) {
        int t = i * 256 + tid;
        float e = energies[b * TT + t];
        if (mask[(size_t)b * TT + t] != 0) e = -1e30f;
        v[i] = e;
        m = fmaxf(m, e);
    }
#pragma unroll
    for (int off = 32; off > 0; off >>= 1) m = fmaxf(m, __shfl_xor(m, off, 64));
    int wave = tid >> 6, lane = tid & 63;
    if (lane == 0) s_red[wave] = m;
    __syncthreads();
    m = fmaxf(fmaxf(s_red[0], s_red[1]), fmaxf(s_red[2], s_red[3]));

    float ssum = 0.f;
#pragma unroll
    for (int i = 0; i < 8; ++i) {
        v[i] = expf(v[i] - m);
        ssum += v[i];
    }
#pragma unroll
    for (int off = 32; off > 0; off >>= 1) ssum += __shfl_xor(ssum, off, 64);
    if (lane == 0) s_red[4 + wave] = ssum;
    __syncthreads();
    float inv = 1.f / (s_red[4] + s_red[5] + s_red[6] + s_red[7]);
#pragma unroll
    for (int i = 0; i < 8; ++i) w[b * TT + i * 256 + tid] = v[i] * inv;
}

// ---------------------------------------------------------------------------
// Kernel 4: partial context over t-segments (deterministic: plain writes)
// grid = B * NSEG, block = 256; thread owns 2 consecutive emb dims (float2)
// ---------------------------------------------------------------------------
__global__ __launch_bounds__(256) void ctx_partial_kernel(
    const float* __restrict__ mem,  // [B][T][EMB]
    const float* __restrict__ w,    // [B][T]
    float* __restrict__ partial)    // [NSEG][B][EMB]
{
    int b = blockIdx.x >> 4;
    int seg = blockIdx.x & 15;
    int tid = threadIdx.x;

    __shared__ float s_w[SEG_T];
    if (tid < SEG_T) s_w[tid] = w[b * TT + seg * SEG_T + tid];
    __syncthreads();

    float2 acc = {0.f, 0.f};
    const float2* m2 =
        (const float2*)(mem + ((size_t)b * TT + (size_t)seg * SEG_T) * EMB) + tid;
#pragma unroll 4
    for (int i = 0; i < SEG_T; ++i) {
        float wv = s_w[i];
        float2 mv = m2[(size_t)i * (EMB / 2)];
        acc.x += wv * mv.x;
        acc.y += wv * mv.y;
    }
    float2* p2 = (float2*)(partial + ((size_t)(seg * BB + b)) * EMB) + tid;
    *p2 = acc;
}

// ---------------------------------------------------------------------------
// Kernel 5: reduce partials -> context
// ---------------------------------------------------------------------------
__global__ __launch_bounds__(256) void ctx_reduce_kernel(
    const float* __restrict__ partial, float* __restrict__ ctx) {
    int idx = blockIdx.x * 256 + threadIdx.x;  // 0 .. B*EMB-1
    float acc = 0.f;
#pragma unroll
    for (int s = 0; s < NSEG; ++s) acc += partial[(size_t)s * (BB * EMB) + idx];
    ctx[idx] = acc;
}

// ---------------------------------------------------------------------------
extern "C" void kernel_launch(void* const* d_in, const int* in_sizes, int n_in,
                              void* d_out, int out_size, void* d_ws, size_t ws_size,
                              hipStream_t stream) {
    const float* h    = (const float*)d_in[0];  // [B][RNN]
    const float* mem  = (const float*)d_in[1];  // [B][T][EMB]
    const float* pmem = (const float*)d_in[2];  // [B][T][ATTN]
    const float* awc  = (const float*)d_in[3];  // [B][2][T]
    const unsigned char* mask = (const unsigned char*)d_in[4];  // [B][T] bool
    const float* Wq   = (const float*)d_in[5];  // [ATTN][RNN]
    const float* Wcv  = (const float*)d_in[6];  // [NF][2][KS]
    const float* Wloc = (const float*)d_in[7];  // [ATTN][NF]
    const float* Wv   = (const float*)d_in[8];  // [1][ATTN]

    float* out = (float*)d_out;
    float* ctx = out;                  // [B][EMB]
    float* wts = out + BB * EMB;       // [B][T]

    float* ws       = (float*)d_ws;
    float* pq       = ws;                          // [B][ATTN]
    float* energies = ws + BB * ATTN;              // [B][T]
    float* partial  = ws + BB * ATTN + BB * TT;    // [NSEG][B][EMB]

    pq_kernel<<<BB, 256, 0, stream>>>(h, Wq, pq);
    energy_kernel<<<BB * (TT / TILE_T), 256, 0, stream>>>(pmem, awc, pq, Wcv,
                                                          Wloc, Wv, energies);
    softmax_kernel<<<BB, 256, 0, stream>>>(energies, mask, wts);
    ctx_partial_kernel<<<BB * NSEG, 256, 0, stream>>>(mem, wts, partial);
    ctx_reduce_kernel<<<(BB * EMB) / 256, 256, 0, stream>>>(partial, ctx);
}

// Round 2
// 143.770 us; speedup vs baseline: 1.0901x; 1.0901x over previous
//
#include <hip/hip_runtime.h>
#include <math.h>

#define BB 64
#define TT 2048
#define RNN 1024
#define EMB 512
#define ATTN 128
#define NF 32
#define KS 31
#define PADW 15

#define TILE_T 128          // energy tile
#define NSEG 16             // ctx t-segments
#define SEG_T (TT / NSEG)   // 128
#define NPART (NSEG * 2)    // 2 row-halves per segment

__device__ __forceinline__ float fast_tanh(float x) {
    // tanh(x) = sign(x) * (1 - e) / (1 + e), e = exp(-2|x|); no overflow.
    float ax = fabsf(x);
    float e = __expf(-2.f * ax);
    float r = (1.f - e) * __builtin_amdgcn_rcpf(1.f + e);
    return copysignf(r, x);
}

// ---------------------------------------------------------------------------
// Kernel 1: pq[b][a] = sum_r h[b][r] * Wq[a][r]
// ---------------------------------------------------------------------------
__global__ __launch_bounds__(256) void pq_kernel(const float* __restrict__ h,
                                                 const float* __restrict__ Wq,
                                                 float* __restrict__ pq) {
    int b = blockIdx.x;
    __shared__ float s_h[RNN];
    for (int i = threadIdx.x; i < RNN; i += 256) s_h[i] = h[b * RNN + i];
    __syncthreads();

    int wave = threadIdx.x >> 6;
    int lane = threadIdx.x & 63;
    for (int j = 0; j < 32; ++j) {
        int a = wave * 32 + j;
        const float4* wq4 = (const float4*)(Wq + (size_t)a * RNN);
        float acc = 0.f;
#pragma unroll
        for (int i = 0; i < 4; ++i) {
            float4 w4 = wq4[lane + 64 * i];
            float4 h4 = *(const float4*)(s_h + 4 * (lane + 64 * i));
            acc += w4.x * h4.x + w4.y * h4.y + w4.z * h4.z + w4.w * h4.w;
        }
#pragma unroll
        for (int off = 32; off > 0; off >>= 1) acc += __shfl_xor(acc, off, 64);
        if (lane == 0) pq[b * ATTN + a] = acc;
    }
}

// ---------------------------------------------------------------------------
// Kernel 2: energies[b][t]
// grid = B * (T/TILE_T) = 1024, block = 256 (4 blocks/CU for latency hiding)
// ---------------------------------------------------------------------------
__global__ __launch_bounds__(256) void energy_kernel(
    const float* __restrict__ pm,     // [B][T][ATTN]
    const float* __restrict__ awc,    // [B][2][T]
    const float* __restrict__ pq,     // [B][ATTN]
    const float* __restrict__ Wconv,  // [NF][2][KS]
    const float* __restrict__ Wloc,   // [ATTN][NF]
    const float* __restrict__ Wv,     // [ATTN]
    float* __restrict__ energies)     // [B][T]
{
    int b = blockIdx.x >> 4;            // 16 tiles per batch row
    int t0 = (blockIdx.x & 15) * TILE_T;
    int tid = threadIdx.x;

    __shared__ float s_awc[2][TILE_T + 2 * PADW];  // 2 x 158
    __shared__ float s_conv[TILE_T][36];           // padded rows, 16B aligned

    for (int i = tid; i < 2 * (TILE_T + 2 * PADW); i += 256) {
        int c = i / (TILE_T + 2 * PADW);
        int j = i % (TILE_T + 2 * PADW);
        int tg = t0 - PADW + j;
        s_awc[c][j] = (tg >= 0 && tg < TT) ? awc[((size_t)b * 2 + c) * TT + tg] : 0.f;
    }
    __syncthreads();

    // ---- phase A: conv. thread = (t = tid&127, filter-half = tid>>7) ----
    {
        int t = tid & 127;
        int fh = tid >> 7;
        float aw[2][KS];
#pragma unroll
        for (int c = 0; c < 2; ++c)
#pragma unroll
            for (int k = 0; k < KS; ++k) aw[c][k] = s_awc[c][t + k];

#pragma unroll
        for (int ff = 0; ff < 16; ++ff) {
            int f = fh * 16 + ff;   // wave-uniform -> scalar Wconv loads
            float acc = 0.f;
#pragma unroll
            for (int c = 0; c < 2; ++c)
#pragma unroll
                for (int k = 0; k < KS; ++k)
                    acc += aw[c][k] * Wconv[(f * 2 + c) * KS + k];
            s_conv[t][f] = acc;
        }
    }
    __syncthreads();

    // ---- phase B: wave owns 32 t, lane owns attn dims (lane, lane+64) ----
    int wave = tid >> 6;
    int lane = tid & 63;

    float wl0[NF], wl1[NF];
#pragma unroll
    for (int f = 0; f < NF; ++f) {
        wl0[f] = Wloc[lane * NF + f];
        wl1[f] = Wloc[(lane + 64) * NF + f];
    }
    float pq0 = pq[b * ATTN + lane], pq1 = pq[b * ATTN + lane + 64];
    float wv0 = Wv[lane], wv1 = Wv[lane + 64];

    float eout = 0.f;
#pragma unroll 2
    for (int i = 0; i < 32; ++i) {
        int tl = wave * 32 + i;
        int tg = t0 + tl;
        float v0 = pq0, v1 = pq1;
        const float4* cv4 = (const float4*)&s_conv[tl][0];  // uniform broadcast
#pragma unroll
        for (int f4 = 0; f4 < 8; ++f4) {
            float4 cv = cv4[f4];
            v0 += cv.x * wl0[f4 * 4 + 0] + cv.y * wl0[f4 * 4 + 1] +
                  cv.z * wl0[f4 * 4 + 2] + cv.w * wl0[f4 * 4 + 3];
            v1 += cv.x * wl1[f4 * 4 + 0] + cv.y * wl1[f4 * 4 + 1] +
                  cv.z * wl1[f4 * 4 + 2] + cv.w * wl1[f4 * 4 + 3];
        }
        const float* pmrow = pm + ((size_t)(b * TT + tg)) * ATTN;
        v0 += pmrow[lane];
        v1 += pmrow[lane + 64];
        float e = wv0 * fast_tanh(v0) + wv1 * fast_tanh(v1);
#pragma unroll
        for (int off = 32; off > 0; off >>= 1) e += __shfl_xor(e, off, 64);
        if (lane == i) eout = e;   // butterfly leaves sum in all lanes
    }
    if (lane < 32) energies[b * TT + t0 + wave * 32 + lane] = eout;
}

// ---------------------------------------------------------------------------
// Kernel 3: softmax over T per row; weights -> d_out
// ---------------------------------------------------------------------------
__global__ __launch_bounds__(256) void softmax_kernel(
    const float* __restrict__ energies, const unsigned char* __restrict__ mask,
    float* __restrict__ w) {
    int b = blockIdx.x, tid = threadIdx.x;
    __shared__ float s_red[8];

    float v[8];
    float m = -1e30f;
#pragma unroll
    for (int i = 0; i < 8; ++i) {
        int t = i * 256 + tid;
        float e = energies[b * TT + t];
        if (mask[(size_t)b * TT + t] != 0) e = -1e30f;
        v[i] = e;
        m = fmaxf(m, e);
    }
#pragma unroll
    for (int off = 32; off > 0; off >>= 1) m = fmaxf(m, __shfl_xor(m, off, 64));
    int wave = tid >> 6, lane = tid & 63;
    if (lane == 0) s_red[wave] = m;
    __syncthreads();
    m = fmaxf(fmaxf(s_red[0], s_red[1]), fmaxf(s_red[2], s_red[3]));

    float ssum = 0.f;
#pragma unroll
    for (int i = 0; i < 8; ++i) {
        v[i] = __expf(v[i] - m);
        ssum += v[i];
    }
#pragma unroll
    for (int off = 32; off > 0; off >>= 1) ssum += __shfl_xor(ssum, off, 64);
    if (lane == 0) s_red[4 + wave] = ssum;
    __syncthreads();
    float inv = 1.f / (s_red[4] + s_red[5] + s_red[6] + s_red[7]);
#pragma unroll
    for (int i = 0; i < 8; ++i) w[b * TT + i * 256 + tid] = v[i] * inv;
}

// ---------------------------------------------------------------------------
// Kernel 4: partial context. grid = B*NSEG, block = 256.
// thread = (emb-quad e4 = tid&127, row-parity = tid>>7); float4 streaming.
// ---------------------------------------------------------------------------
__global__ __launch_bounds__(256) void ctx_partial_kernel(
    const float* __restrict__ mem,  // [B][T][EMB]
    const float* __restrict__ w,    // [B][T]
    float* __restrict__ partial)    // [NPART][B][EMB]
{
    int b = blockIdx.x >> 4;
    int seg = blockIdx.x & 15;
    int tid = threadIdx.x;
    int e4 = tid & 127;    // float4 index into 512-dim emb
    int half = tid >> 7;   // row parity

    __shared__ float s_w[SEG_T];
    if (tid < SEG_T) s_w[tid] = w[b * TT + seg * SEG_T + tid];
    __syncthreads();

    float4 acc = {0.f, 0.f, 0.f, 0.f};
    const float4* m4 = (const float4*)(mem + ((size_t)b * TT + (size_t)seg * SEG_T) * EMB)
                       + (size_t)half * (EMB / 4) + e4;
#pragma unroll 4
    for (int i = 0; i < SEG_T / 2; ++i) {
        float wv = s_w[2 * i + half];
        float4 mv = m4[(size_t)i * (2 * EMB / 4)];
        acc.x += wv * mv.x;
        acc.y += wv * mv.y;
        acc.z += wv * mv.z;
        acc.w += wv * mv.w;
    }
    float4* p4 = (float4*)(partial + ((size_t)(seg * 2 + half) * BB + b) * EMB) + e4;
    *p4 = acc;
}

// ---------------------------------------------------------------------------
// Kernel 5: reduce partials -> context
// ---------------------------------------------------------------------------
__global__ __launch_bounds__(256) void ctx_reduce_kernel(
    const float* __restrict__ partial, float* __restrict__ ctx) {
    int idx = blockIdx.x * 256 + threadIdx.x;  // 0 .. B*EMB-1
    float acc = 0.f;
#pragma unroll
    for (int s = 0; s < NPART; ++s) acc += partial[(size_t)s * (BB * EMB) + idx];
    ctx[idx] = acc;
}

// ---------------------------------------------------------------------------
extern "C" void kernel_launch(void* const* d_in, const int* in_sizes, int n_in,
                              void* d_out, int out_size, void* d_ws, size_t ws_size,
                              hipStream_t stream) {
    const float* h    = (const float*)d_in[0];
    const float* mem  = (const float*)d_in[1];
    const float* pmem = (const float*)d_in[2];
    const float* awc  = (const float*)d_in[3];
    const unsigned char* mask = (const unsigned char*)d_in[4];
    const float* Wq   = (const float*)d_in[5];
    const float* Wcv  = (const float*)d_in[6];
    const float* Wloc = (const float*)d_in[7];
    const float* Wv   = (const float*)d_in[8];

    float* out = (float*)d_out;
    float* ctx = out;                  // [B][EMB]
    float* wts = out + BB * EMB;       // [B][T]

    float* ws       = (float*)d_ws;
    float* pq       = ws;                          // [B][ATTN]
    float* energies = ws + BB * ATTN;              // [B][T]
    float* partial  = ws + BB * ATTN + BB * TT;    // [NPART][B][EMB]

    pq_kernel<<<BB, 256, 0, stream>>>(h, Wq, pq);
    energy_kernel<<<BB * (TT / TILE_T), 256, 0, stream>>>(pmem, awc, pq, Wcv,
                                                          Wloc, Wv, energies);
    softmax_kernel<<<BB, 256, 0, stream>>>(energies, mask, wts);
    ctx_partial_kernel<<<BB * NSEG, 256, 0, stream>>>(mem, wts, partial);
    ctx_reduce_kernel<<<(BB * EMB) / 256, 256, 0, stream>>>(partial, ctx);
}

// Round 3
// 135.449 us; speedup vs baseline: 1.1571x; 1.0614x over previous
//
#include <hip/hip_runtime.h>
#include <math.h>

#define BB 64
#define TT 2048
#define RNN 1024
#define EMB 512
#define ATTN 128
#define NF 32
#define KS 31
#define PADW 15

#define CHUNK 128
#define NCH (TT / CHUNK)  // 16

__device__ __forceinline__ float fast_tanh(float x) {
    float ax = fabsf(x);
    float e = __expf(-2.f * ax);
    float r = (1.f - e) * __builtin_amdgcn_rcpf(1.f + e);
    return copysignf(r, x);
}

// ---------------------------------------------------------------------------
// Kernel 1: pq[b][a] = sum_r h[b][r] * Wq[a][r]
// grid = B*4 (block owns 32 outputs), block = 256; wave does 8 outputs
// ---------------------------------------------------------------------------
__global__ __launch_bounds__(256) void pq_kernel(const float* __restrict__ h,
                                                 const float* __restrict__ Wq,
                                                 float* __restrict__ pq) {
    int b = blockIdx.x >> 2;
    int q = blockIdx.x & 3;
    __shared__ float s_h[RNN];
    for (int i = threadIdx.x; i < RNN; i += 256) s_h[i] = h[b * RNN + i];
    __syncthreads();

    int wave = threadIdx.x >> 6;
    int lane = threadIdx.x & 63;
#pragma unroll 2
    for (int j = 0; j < 8; ++j) {
        int a = q * 32 + wave * 8 + j;
        const float4* wq4 = (const float4*)(Wq + (size_t)a * RNN);
        float acc = 0.f;
#pragma unroll
        for (int i = 0; i < 4; ++i) {
            float4 w4 = wq4[lane + 64 * i];
            float4 h4 = *(const float4*)(s_h + 4 * (lane + 64 * i));
            acc += w4.x * h4.x + w4.y * h4.y + w4.z * h4.z + w4.w * h4.w;
        }
#pragma unroll
        for (int off = 32; off > 0; off >>= 1) acc += __shfl_xor(acc, off, 64);
        if (lane == 0) pq[b * ATTN + a] = acc;
    }
}

// ---------------------------------------------------------------------------
// Kernel 2 (fused): per (b, chunk of 128 t):
//   conv -> energies -> chunk max m_c -> p=exp(e-m_c) (masked->0 via -1e30)
//   -> wp (unnormalized weights), (m_c, s_c) -> partial ctx = sum_t p_t*mem_t
// grid = B*NCH = 1024, block = 256
// ---------------------------------------------------------------------------
__global__ __launch_bounds__(256) void fused_kernel(
    const float* __restrict__ pm,     // [B][T][ATTN]
    const float* __restrict__ awc,    // [B][2][T]
    const float* __restrict__ mem,    // [B][T][EMB]
    const unsigned char* __restrict__ mask,  // [B][T]
    const float* __restrict__ pq,     // [B][ATTN]
    const float* __restrict__ Wconv,  // [NF][2][KS]
    const float* __restrict__ Wloc,   // [ATTN][NF]
    const float* __restrict__ Wv,     // [ATTN]
    float* __restrict__ wp,           // [B][T] unnormalized exp
    float* __restrict__ ms,           // [B][NCH][2] (m, s)
    float* __restrict__ cp)           // [2*NCH][B][EMB] partial ctx
{
    int b = blockIdx.x >> 4;
    int ch = blockIdx.x & 15;
    int t0 = ch * CHUNK;
    int tid = threadIdx.x;

    __shared__ float s_awc[2][CHUNK + 2 * PADW];
    __shared__ float s_conv[CHUNK][36];
    __shared__ float s_e[CHUNK];
    __shared__ float s_p[CHUNK];

    // stage awc window
    for (int i = tid; i < 2 * (CHUNK + 2 * PADW); i += 256) {
        int c = i / (CHUNK + 2 * PADW);
        int j = i % (CHUNK + 2 * PADW);
        int tg = t0 - PADW + j;
        s_awc[c][j] = (tg >= 0 && tg < TT) ? awc[((size_t)b * 2 + c) * TT + tg] : 0.f;
    }
    __syncthreads();

    // ---- conv: thread = (t = tid&127, filter-half = tid>>7) ----
    {
        int t = tid & 127;
        int fh = tid >> 7;
        float aw[2][KS];
#pragma unroll
        for (int c = 0; c < 2; ++c)
#pragma unroll
            for (int k = 0; k < KS; ++k) aw[c][k] = s_awc[c][t + k];
#pragma unroll
        for (int ff = 0; ff < 16; ++ff) {
            int f = fh * 16 + ff;  // wave-uniform -> scalar loads
            float acc = 0.f;
#pragma unroll
            for (int c = 0; c < 2; ++c)
#pragma unroll
                for (int k = 0; k < KS; ++k)
                    acc += aw[c][k] * Wconv[(f * 2 + c) * KS + k];
            s_conv[t][f] = acc;
        }
    }
    __syncthreads();

    // ---- energies: wave owns 32 t, lane owns attn dims (lane, lane+64) ----
    int wave = tid >> 6;
    int lane = tid & 63;

    float wl0[NF], wl1[NF];
#pragma unroll
    for (int f = 0; f < NF; ++f) {
        wl0[f] = Wloc[lane * NF + f];
        wl1[f] = Wloc[(lane + 64) * NF + f];
    }
    float pq0 = pq[b * ATTN + lane], pq1 = pq[b * ATTN + lane + 64];
    float wv0 = Wv[lane], wv1 = Wv[lane + 64];

    float eout = 0.f;
#pragma unroll 2
    for (int i = 0; i < 32; ++i) {
        int tl = wave * 32 + i;
        int tg = t0 + tl;
        float v0 = pq0, v1 = pq1;
        const float4* cv4 = (const float4*)&s_conv[tl][0];
#pragma unroll
        for (int f4 = 0; f4 < 8; ++f4) {
            float4 cv = cv4[f4];
            v0 += cv.x * wl0[f4 * 4 + 0] + cv.y * wl0[f4 * 4 + 1] +
                  cv.z * wl0[f4 * 4 + 2] + cv.w * wl0[f4 * 4 + 3];
            v1 += cv.x * wl1[f4 * 4 + 0] + cv.y * wl1[f4 * 4 + 1] +
                  cv.z * wl1[f4 * 4 + 2] + cv.w * wl1[f4 * 4 + 3];
        }
        const float* pmrow = pm + ((size_t)(b * TT + tg)) * ATTN;
        v0 += pmrow[lane];
        v1 += pmrow[lane + 64];
        float e = wv0 * fast_tanh(v0) + wv1 * fast_tanh(v1);
#pragma unroll
        for (int off = 32; off > 0; off >>= 1) e += __shfl_xor(e, off, 64);
        if (lane == i) eout = e;
    }
    if (lane < 32) {
        int tl = wave * 32 + lane;
        float e = eout;
        if (mask[(size_t)b * TT + t0 + tl] != 0) e = -1e30f;
        s_e[tl] = e;
    }
    __syncthreads();

    // chunk max (each wave computes redundantly from LDS)
    float m = fmaxf(s_e[lane], s_e[lane + 64]);
#pragma unroll
    for (int off = 32; off > 0; off >>= 1) m = fmaxf(m, __shfl_xor(m, off, 64));

    // p = exp(e - m), store LDS + global (unnormalized)
    if (tid < CHUNK) {
        float p = __expf(s_e[tid] - m);
        s_p[tid] = p;
        wp[(size_t)b * TT + t0 + tid] = p;
    }
    __syncthreads();

    // chunk sum (redundant per wave)
    float ssum = s_p[lane] + s_p[lane + 64];
#pragma unroll
    for (int off = 32; off > 0; off >>= 1) ssum += __shfl_xor(ssum, off, 64);
    if (tid == 0) {
        ms[(b * NCH + ch) * 2 + 0] = m;
        ms[(b * NCH + ch) * 2 + 1] = ssum;
    }

    // ---- partial ctx: thread = (e4 = tid&127, row-parity = tid>>7) ----
    int e4 = tid & 127;
    int half = tid >> 7;
    float4 acc = {0.f, 0.f, 0.f, 0.f};
    const float4* m4 = (const float4*)(mem + ((size_t)b * TT + t0) * EMB) +
                       (size_t)half * (EMB / 4) + e4;
#pragma unroll 8
    for (int i = 0; i < CHUNK / 2; ++i) {
        float pv = s_p[2 * i + half];
        float4 mv = m4[(size_t)i * (2 * EMB / 4)];
        acc.x += pv * mv.x;
        acc.y += pv * mv.y;
        acc.z += pv * mv.z;
        acc.w += pv * mv.w;
    }
    float4* cp4 = (float4*)(cp + ((size_t)((ch * 2 + half) * BB + b)) * EMB) + e4;
    *cp4 = acc;
}

// ---------------------------------------------------------------------------
// Kernel 3: combine. grid = B, block = 256.
//   M = max m_c; S = sum s_c*exp(m_c-M); scale_c = exp(m_c-M)/S
//   ctx = sum_c scale_{c} * cp[c];  wts = wp * scale_{chunk(t)}
// ---------------------------------------------------------------------------
__global__ __launch_bounds__(256) void combine_kernel(
    const float* __restrict__ wp, const float* __restrict__ ms,
    const float* __restrict__ cp, float* __restrict__ ctx,
    float* __restrict__ wts) {
    int b = blockIdx.x;
    int tid = threadIdx.x;
    __shared__ float s_m[NCH], s_s[NCH], s_scale[NCH];
    if (tid < NCH) {
        s_m[tid] = ms[(b * NCH + tid) * 2 + 0];
        s_s[tid] = ms[(b * NCH + tid) * 2 + 1];
    }
    __syncthreads();
    float M = -1e30f;
#pragma unroll
    for (int c = 0; c < NCH; ++c) M = fmaxf(M, s_m[c]);
    float S = 0.f;
#pragma unroll
    for (int c = 0; c < NCH; ++c) S += s_s[c] * __expf(s_m[c] - M);
    float invS = 1.f / S;
    if (tid < NCH) s_scale[tid] = __expf(s_m[tid] - M) * invS;
    __syncthreads();

    if (tid < 128) {
        float4 acc = {0.f, 0.f, 0.f, 0.f};
#pragma unroll 8
        for (int c = 0; c < 2 * NCH; ++c) {
            float sc = s_scale[c >> 1];
            float4 v = *((const float4*)(cp + ((size_t)(c * BB + b)) * EMB) + tid);
            acc.x += sc * v.x;
            acc.y += sc * v.y;
            acc.z += sc * v.z;
            acc.w += sc * v.w;
        }
        *((float4*)(ctx + (size_t)b * EMB) + tid) = acc;
    }
#pragma unroll
    for (int i = 0; i < 8; ++i) {
        int t = i * 256 + tid;
        wts[(size_t)b * TT + t] = wp[(size_t)b * TT + t] * s_scale[t >> 7];
    }
}

// ---------------------------------------------------------------------------
extern "C" void kernel_launch(void* const* d_in, const int* in_sizes, int n_in,
                              void* d_out, int out_size, void* d_ws, size_t ws_size,
                              hipStream_t stream) {
    const float* h    = (const float*)d_in[0];
    const float* mem  = (const float*)d_in[1];
    const float* pmem = (const float*)d_in[2];
    const float* awc  = (const float*)d_in[3];
    const unsigned char* mask = (const unsigned char*)d_in[4];
    const float* Wq   = (const float*)d_in[5];
    const float* Wcv  = (const float*)d_in[6];
    const float* Wloc = (const float*)d_in[7];
    const float* Wv   = (const float*)d_in[8];

    float* out = (float*)d_out;
    float* ctx = out;             // [B][EMB]
    float* wts = out + BB * EMB;  // [B][T]

    float* ws = (float*)d_ws;
    float* pq = ws;                              // [B][ATTN]
    float* wp = pq + BB * ATTN;                  // [B][T]
    float* ms = wp + BB * TT;                    // [B][NCH][2]
    float* cp = ms + BB * NCH * 2;               // [2*NCH][B][EMB]

    pq_kernel<<<BB * 4, 256, 0, stream>>>(h, Wq, pq);
    fused_kernel<<<BB * NCH, 256, 0, stream>>>(pmem, awc, mem, mask, pq, Wcv,
                                               Wloc, Wv, wp, ms, cp);
    combine_kernel<<<BB, 256, 0, stream>>>(wp, ms, cp, ctx, wts);
}

// Round 4
// 126.434 us; speedup vs baseline: 1.2396x; 1.0713x over previous
//
#include <hip/hip_runtime.h>
#include <math.h>

#define BB 64
#define TT 2048
#define RNN 1024
#define EMB 512
#define ATTN 128
#define NF 32
#define KS 31
#define PADW 15

#define CHUNK 64
#define NCH (TT / CHUNK)  // 32

__device__ __forceinline__ float fast_tanh(float x) {
    float ax = fabsf(x);
    float e = __expf(-2.f * ax);
    float r = (1.f - e) * __builtin_amdgcn_rcpf(1.f + e);
    return copysignf(r, x);
}

// ---------------------------------------------------------------------------
// Kernel 1: pq[b][a] = sum_r h[b][r] * Wq[a][r]
// grid = B*4, block = 256; wave does 8 outputs
// ---------------------------------------------------------------------------
__global__ __launch_bounds__(256) void pq_kernel(const float* __restrict__ h,
                                                 const float* __restrict__ Wq,
                                                 float* __restrict__ pq) {
    int b = blockIdx.x >> 2;
    int q = blockIdx.x & 3;
    __shared__ float s_h[RNN];
    for (int i = threadIdx.x; i < RNN; i += 256) s_h[i] = h[b * RNN + i];
    __syncthreads();

    int wave = threadIdx.x >> 6;
    int lane = threadIdx.x & 63;
#pragma unroll 2
    for (int j = 0; j < 8; ++j) {
        int a = q * 32 + wave * 8 + j;
        const float4* wq4 = (const float4*)(Wq + (size_t)a * RNN);
        float acc = 0.f;
#pragma unroll
        for (int i = 0; i < 4; ++i) {
            float4 w4 = wq4[lane + 64 * i];
            float4 h4 = *(const float4*)(s_h + 4 * (lane + 64 * i));
            acc += w4.x * h4.x + w4.y * h4.y + w4.z * h4.z + w4.w * h4.w;
        }
#pragma unroll
        for (int off = 32; off > 0; off >>= 1) acc += __shfl_xor(acc, off, 64);
        if (lane == 0) pq[b * ATTN + a] = acc;
    }
}

// ---------------------------------------------------------------------------
// Kernel 2 (fused): per (b, chunk of 64 t):
//   conv -> energies -> chunk (m,s), p=exp(e-m) -> partial ctx
// grid = B*NCH = 2048 blocks (8 blocks/CU), block = 256
// ---------------------------------------------------------------------------
__global__ __launch_bounds__(256) void fused_kernel(
    const float* __restrict__ pm,     // [B][T][ATTN]
    const float* __restrict__ awc,    // [B][2][T]
    const float* __restrict__ mem,    // [B][T][EMB]
    const unsigned char* __restrict__ mask,  // [B][T]
    const float* __restrict__ pq,     // [B][ATTN]
    const float* __restrict__ Wconv,  // [NF][2][KS]
    const float* __restrict__ Wloc,   // [ATTN][NF]
    const float* __restrict__ Wv,     // [ATTN]
    float* __restrict__ wp,           // [B][T] unnormalized exp
    float* __restrict__ ms,           // [B][NCH][2] (m, s)
    float* __restrict__ cp)           // [2*NCH][B][EMB] partial ctx
{
    int b = blockIdx.x >> 5;
    int ch = blockIdx.x & 31;
    int t0 = ch * CHUNK;
    int tid = threadIdx.x;

    __shared__ float s_awc[2][CHUNK + 2 * PADW];  // 2 x 94
    __shared__ float s_conv[CHUNK][36];
    __shared__ float s_e[CHUNK];
    __shared__ float s_p[CHUNK];

    // stage awc window
    for (int i = tid; i < 2 * (CHUNK + 2 * PADW); i += 256) {
        int c = i / (CHUNK + 2 * PADW);
        int j = i % (CHUNK + 2 * PADW);
        int tg = t0 - PADW + j;
        s_awc[c][j] = (tg >= 0 && tg < TT) ? awc[((size_t)b * 2 + c) * TT + tg] : 0.f;
    }
    __syncthreads();

    // ---- conv: thread = (t = tid&63, filter-group fh = tid>>6, 8 filt each) --
    {
        int t = tid & 63;
        int fh = tid >> 6;  // wave index -> wave-uniform
        float aw[2][KS];
#pragma unroll
        for (int c = 0; c < 2; ++c)
#pragma unroll
            for (int k = 0; k < KS; ++k) aw[c][k] = s_awc[c][t + k];
#pragma unroll
        for (int ff = 0; ff < 8; ++ff) {
            int f = fh * 8 + ff;  // wave-uniform -> scalar Wconv loads
            float acc = 0.f;
#pragma unroll
            for (int c = 0; c < 2; ++c)
#pragma unroll
                for (int k = 0; k < KS; ++k)
                    acc += aw[c][k] * Wconv[(f * 2 + c) * KS + k];
            s_conv[t][f] = acc;
        }
    }
    __syncthreads();

    // ---- energies: wave owns 16 t, lane owns attn dims (lane, lane+64) ----
    int wave = tid >> 6;
    int lane = tid & 63;

    float wl0[NF], wl1[NF];
#pragma unroll
    for (int f = 0; f < NF; ++f) {
        wl0[f] = Wloc[lane * NF + f];
        wl1[f] = Wloc[(lane + 64) * NF + f];
    }
    float pq0 = pq[b * ATTN + lane], pq1 = pq[b * ATTN + lane + 64];
    float wv0 = Wv[lane], wv1 = Wv[lane + 64];

    float eout = 0.f;
#pragma unroll 2
    for (int i = 0; i < 16; ++i) {
        int tl = wave * 16 + i;
        int tg = t0 + tl;
        float v0 = pq0, v1 = pq1;
        const float4* cv4 = (const float4*)&s_conv[tl][0];  // uniform broadcast
#pragma unroll
        for (int f4 = 0; f4 < 8; ++f4) {
            float4 cv = cv4[f4];
            v0 += cv.x * wl0[f4 * 4 + 0] + cv.y * wl0[f4 * 4 + 1] +
                  cv.z * wl0[f4 * 4 + 2] + cv.w * wl0[f4 * 4 + 3];
            v1 += cv.x * wl1[f4 * 4 + 0] + cv.y * wl1[f4 * 4 + 1] +
                  cv.z * wl1[f4 * 4 + 2] + cv.w * wl1[f4 * 4 + 3];
        }
        const float* pmrow = pm + ((size_t)(b * TT + tg)) * ATTN;
        v0 += pmrow[lane];
        v1 += pmrow[lane + 64];
        float e = wv0 * fast_tanh(v0) + wv1 * fast_tanh(v1);
#pragma unroll
        for (int off = 32; off > 0; off >>= 1) e += __shfl_xor(e, off, 64);
        if (lane == i) eout = e;  // butterfly leaves sum in all lanes
    }
    if (lane < 16) {
        int tl = wave * 16 + lane;
        float e = eout;
        if (mask[(size_t)b * TT + t0 + tl] != 0) e = -1e30f;
        s_e[tl] = e;
    }
    __syncthreads();

    // chunk max (redundant per wave; only first 64 entries matter)
    float m = s_e[lane];
#pragma unroll
    for (int off = 32; off > 0; off >>= 1) m = fmaxf(m, __shfl_xor(m, off, 64));

    // p = exp(e - m)
    if (tid < CHUNK) {
        float p = __expf(s_e[tid] - m);
        s_p[tid] = p;
        wp[(size_t)b * TT + t0 + tid] = p;
    }
    __syncthreads();

    // chunk sum (redundant per wave)
    float ssum = s_p[lane];
#pragma unroll
    for (int off = 32; off > 0; off >>= 1) ssum += __shfl_xor(ssum, off, 64);
    if (tid == 0) {
        ms[(b * NCH + ch) * 2 + 0] = m;
        ms[(b * NCH + ch) * 2 + 1] = ssum;
    }

    // ---- partial ctx: thread = (e4 = tid&127, row-parity = tid>>7) ----
    int e4 = tid & 127;
    int half = tid >> 7;
    float4 acc = {0.f, 0.f, 0.f, 0.f};
    const float4* m4 = (const float4*)(mem + ((size_t)b * TT + t0) * EMB) +
                       (size_t)half * (EMB / 4) + e4;
#pragma unroll 8
    for (int i = 0; i < CHUNK / 2; ++i) {
        float pv = s_p[2 * i + half];
        float4 mv = m4[(size_t)i * (2 * EMB / 4)];
        acc.x += pv * mv.x;
        acc.y += pv * mv.y;
        acc.z += pv * mv.z;
        acc.w += pv * mv.w;
    }
    float4* cp4 = (float4*)(cp + ((size_t)((ch * 2 + half) * BB + b)) * EMB) + e4;
    *cp4 = acc;
}

// ---------------------------------------------------------------------------
// Kernel 3: combine. grid = B, block = 256.
// ---------------------------------------------------------------------------
__global__ __launch_bounds__(256) void combine_kernel(
    const float* __restrict__ wp, const float* __restrict__ ms,
    const float* __restrict__ cp, float* __restrict__ ctx,
    float* __restrict__ wts) {
    int b = blockIdx.x;
    int tid = threadIdx.x;
    __shared__ float s_m[NCH], s_s[NCH], s_scale[NCH];
    if (tid < NCH) {
        s_m[tid] = ms[(b * NCH + tid) * 2 + 0];
        s_s[tid] = ms[(b * NCH + tid) * 2 + 1];
    }
    __syncthreads();
    float M = -1e30f;
#pragma unroll
    for (int c = 0; c < NCH; ++c) M = fmaxf(M, s_m[c]);
    float S = 0.f;
#pragma unroll
    for (int c = 0; c < NCH; ++c) S += s_s[c] * __expf(s_m[c] - M);
    float invS = 1.f / S;
    if (tid < NCH) s_scale[tid] = __expf(s_m[tid] - M) * invS;
    __syncthreads();

    if (tid < 128) {
        float4 acc = {0.f, 0.f, 0.f, 0.f};
#pragma unroll 8
        for (int c = 0; c < 2 * NCH; ++c) {
            float sc = s_scale[c >> 1];
            float4 v = *((const float4*)(cp + ((size_t)(c * BB + b)) * EMB) + tid);
            acc.x += sc * v.x;
            acc.y += sc * v.y;
            acc.z += sc * v.z;
            acc.w += sc * v.w;
        }
        *((float4*)(ctx + (size_t)b * EMB) + tid) = acc;
    }
#pragma unroll
    for (int i = 0; i < 8; ++i) {
        int t = i * 256 + tid;
        wts[(size_t)b * TT + t] = wp[(size_t)b * TT + t] * s_scale[t >> 6];
    }
}

// ---------------------------------------------------------------------------
extern "C" void kernel_launch(void* const* d_in, const int* in_sizes, int n_in,
                              void* d_out, int out_size, void* d_ws, size_t ws_size,
                              hipStream_t stream) {
    const float* h    = (const float*)d_in[0];
    const float* mem  = (const float*)d_in[1];
    const float* pmem = (const float*)d_in[2];
    const float* awc  = (const float*)d_in[3];
    const unsigned char* mask = (const unsigned char*)d_in[4];
    const float* Wq   = (const float*)d_in[5];
    const float* Wcv  = (const float*)d_in[6];
    const float* Wloc = (const float*)d_in[7];
    const float* Wv   = (const float*)d_in[8];

    float* out = (float*)d_out;
    float* ctx = out;             // [B][EMB]
    float* wts = out + BB * EMB;  // [B][T]

    float* ws = (float*)d_ws;
    float* pq = ws;                 // [B][ATTN]
    float* wp = pq + BB * ATTN;     // [B][T]
    float* ms = wp + BB * TT;       // [B][NCH][2]
    float* cp = ms + BB * NCH * 2;  // [2*NCH][B][EMB]

    pq_kernel<<<BB * 4, 256, 0, stream>>>(h, Wq, pq);
    fused_kernel<<<BB * NCH, 256, 0, stream>>>(pmem, awc, mem, mask, pq, Wcv,
                                               Wloc, Wv, wp, ms, cp);
    combine_kernel<<<BB, 256, 0, stream>>>(wp, ms, cp, ctx, wts);
}